// Round 5
// baseline (764.971 us; speedup 1.0000x reference)
//
#include <hip/hip_runtime.h>

#define NT 8192
#define DD 1024
#define HH 4096
#define EE 8
#define RB (NT / 4)   // router blocks inside prep_kernel

typedef __attribute__((ext_vector_type(8))) short short8;
typedef __attribute__((ext_vector_type(4))) float f32x4;

__device__ __forceinline__ unsigned short f2bf(float f) {
    unsigned int u = __float_as_uint(f);
    u += 0x7FFFu + ((u >> 16) & 1u);   // round-to-nearest-even
    return (unsigned short)(u >> 16);
}

__device__ __forceinline__ short8 cvt8(float4 a, float4 b) {
    short8 r;
    r[0] = (short)f2bf(a.x); r[1] = (short)f2bf(a.y);
    r[2] = (short)f2bf(a.z); r[3] = (short)f2bf(a.w);
    r[4] = (short)f2bf(b.x); r[5] = (short)f2bf(b.y);
    r[6] = (short)f2bf(b.z); r[7] = (short)f2bf(b.w);
    return r;
}

__device__ __forceinline__ void gload_lds16(const void* g, void* l) {
    __builtin_amdgcn_global_load_lds(
        (const __attribute__((address_space(1))) unsigned int*)g,
        (__attribute__((address_space(3))) unsigned int*)l, 16, 0, 0);
}

// ---- prep: router (blocks 0..RB-1) + fp32->bf16 weight convert (rest) ----
// Router is tiny compute; cvtw is BW-bound. Fusing them in one launch lets
// router's latency hide under cvtw's streaming blocks (saves one dispatch +
// serialization of ~router time).
__global__ __launch_bounds__(256) void prep_kernel(const float* __restrict__ x,
                                                   const float* __restrict__ Wr,
                                                   const float* __restrict__ br,
                                                   const float* __restrict__ Wup,
                                                   const float* __restrict__ Wdown,
                                                   int* __restrict__ counts,
                                                   int* __restrict__ tlist,
                                                   unsigned short* __restrict__ Wub,
                                                   unsigned short* __restrict__ Wdb) {
    __shared__ float sW[EE * DD];  // 32 KB (router blocks only)
    const int t = threadIdx.x;
    if (blockIdx.x < RB) {
        // ---- router: one wave per token; argmax of x @ Wr^T + br ----
        for (int i = t; i < EE * DD / 4; i += 256)
            ((float4*)sW)[i] = ((const float4*)Wr)[i];
        __syncthreads();
        const int lane = t & 63;
        const int wv = t >> 6;
        const int token = blockIdx.x * 4 + wv;
        const float* xr = x + (size_t)token * DD;
        float acc[EE];
#pragma unroll
        for (int e = 0; e < EE; e++) acc[e] = 0.f;
        for (int k = lane; k < DD; k += 64) {
            float xv = xr[k];
#pragma unroll
            for (int e = 0; e < EE; e++) acc[e] += xv * sW[e * DD + k];
        }
#pragma unroll
        for (int off = 32; off > 0; off >>= 1) {
#pragma unroll
            for (int e = 0; e < EE; e++) acc[e] += __shfl_xor(acc[e], off);
        }
        if (lane == 0) {
            int best = 0;
            float bv = acc[0] + br[0];
#pragma unroll
            for (int e = 1; e < EE; e++) {
                float v = acc[e] + br[e];
                if (v > bv) { bv = v; best = e; }   // strict > == first-max (jnp.argmax)
            }
            int pos = atomicAdd(&counts[best], 1);
            tlist[best * NT + pos] = token;
        }
    } else {
        // ---- weight convert: 8 floats/thread ----
        const size_t half = (size_t)EE * HH * DD;
        size_t i = ((size_t)(blockIdx.x - RB) * 256 + t) * 8;
        const float* s; unsigned short* d;
        if (i < half) { s = Wup + i; d = Wub + i; }
        else          { s = Wdown + (i - half); d = Wdb + (i - half); }
        float4 v0 = ((const float4*)s)[0];
        float4 v1 = ((const float4*)s)[1];
        *(short8*)d = cvt8(v0, v1);
    }
}

// Slot-compacted grids. blockIdx->slot decodes (expert e, row block m0) via a
// prefix over ceil(counts/128).
//
// down_gemm uses an XCD-aware REGION map (round 4: verified, down 148->~134,
// left top-5): region = 4 slots x 8 n-blocks (32 blocks) pinned to ONE XCD's
// 32 CUs via lin = g*256 + i*8 + rm; id space 768, r>=18 early-out.
//
// LDS (BK=32, double-buffered, 32 KB total): rows of 32 bf16 (64 B); logical
// chunk k of row r stored at slot k ^ ((r>>1)&3). B staging stays LDS-linear
// (global_load_lds constraint) with the swizzle applied by permuting the
// per-thread GLOBAL source chunk. A (up_gemm) is reg-staged from x with tlist
// indirection + in-register fp32->bf16 (gather kernel eliminated): loads
// issued right after the barrier, convert+ds_write after the MFMA block
// (T14 issue-early / write-late). One __syncthreads per K-step.

#define SLOTS 72

struct SlotDec { int e, off_e, cnt, m0, ok; };

__device__ __forceinline__ SlotDec decode_slot(const int* __restrict__ counts, int slot) {
    SlotDec d; d.ok = 0; d.e = 0; d.off_e = 0; d.cnt = 0; d.m0 = 0;
    int s = 0, csum = 0;
#pragma unroll
    for (int k = 0; k < EE; k++) {
        int ck = counts[k];
        int mb = (ck + 127) >> 7;
        if (!d.ok && slot < csum + mb) {
            d.ok = 1; d.e = k; d.off_e = s; d.cnt = ck; d.m0 = (slot - csum) * 128;
        }
        s += ck; csum += mb;
    }
    return d;
}

// ---- up GEMM: h = silu(x[tlist] @ Wup[e]^T + bup[e]), bf16 out ----
__global__ __launch_bounds__(256) void up_gemm(const float* __restrict__ x,
                                               const int* __restrict__ tlist,
                                               const unsigned short* __restrict__ Wub,
                                               const float* __restrict__ bup,
                                               const int* __restrict__ counts,
                                               unsigned short* __restrict__ hbuf) {
    SlotDec sd = decode_slot(counts, blockIdx.y);
    if (!sd.ok) return;
    const int e = sd.e, off_e = sd.off_e, cnt = sd.cnt, m0 = sd.m0;
    const int n0 = blockIdx.x * 128;
    const int t = threadIdx.x;

    __shared__ unsigned short sA[2][128 * 32];   // 2 x 8 KB
    __shared__ unsigned short sB[2][128 * 32];   // 2 x 8 KB

    const int r0 = t >> 2;                      // row within 64-row half
    const int kc = (t & 3) ^ ((r0 >> 1) & 3);   // swizzled chunk this thread fetches
    const int c1 = cnt - 1;
    int ra = m0 + r0;      if (ra > c1) ra = c1;   // clamp tail rows (masked on store)
    int rb = m0 + 64 + r0; if (rb > c1) rb = c1;
    const int* tl = tlist + e * NT;
    const float* pA0 = x + (size_t)tl[ra] * DD + kc * 8;   // fp32 source, chunk = 8 elems
    const float* pA1 = x + (size_t)tl[rb] * DD + kc * 8;
    const unsigned short* gB0 = Wub + ((size_t)e * HH + n0 + r0) * DD + kc * 8;
    const unsigned short* gB1 = Wub + ((size_t)e * HH + n0 + 64 + r0) * DD + kc * 8;

    const int lane = t & 63;
    const int wm = ((t >> 6) & 1) * 64;
    const int wn = (t >> 7) * 64;
    const int mrow = lane & 15;
    const int kq = lane >> 4;
    const int slot = (kq ^ ((mrow >> 1) & 3)) * 8;   // swizzled read slot

    f32x4 acc[4][4];
#pragma unroll
    for (int i = 0; i < 4; i++)
#pragma unroll
        for (int j = 0; j < 4; j++)
            acc[i][j] = (f32x4){0.f, 0.f, 0.f, 0.f};

    float4 fa0, fa1, fa2, fa3;                   // in-flight A (fp32)
    auto ALOAD = [&](int kt) {                   // issue early (after barrier)
        fa0 = *(const float4*)(pA0 + kt);
        fa1 = *(const float4*)(pA0 + kt + 4);
        fa2 = *(const float4*)(pA1 + kt);
        fa3 = *(const float4*)(pA1 + kt + 4);
    };
    auto AWRITE = [&](int buf) {                 // convert + write late (after MFMA)
        *(short8*)&sA[buf][t * 8]         = cvt8(fa0, fa1);
        *(short8*)&sA[buf][(t + 256) * 8] = cvt8(fa2, fa3);
    };
    auto BSTAGE = [&](int buf, int kt) {
        gload_lds16(gB0 + kt, &sB[buf][t * 8]);
        gload_lds16(gB1 + kt, &sB[buf][(t + 256) * 8]);
    };

    ALOAD(0); BSTAGE(0, 0); AWRITE(0);
    int cur = 0;
    for (int kt = 0; kt < DD; kt += 32) {
        __syncthreads();                       // stage(cur) complete; cur^1 reads done
        if (kt + 32 < DD) { ALOAD(kt + 32); BSTAGE(cur ^ 1, kt + 32); }
        short8 a[4], b[4];
#pragma unroll
        for (int i = 0; i < 4; i++) {
            a[i] = *(const short8*)(&sA[cur][(wm + i * 16 + mrow) * 32 + slot]);
            b[i] = *(const short8*)(&sB[cur][(wn + i * 16 + mrow) * 32 + slot]);
        }
#pragma unroll
        for (int i = 0; i < 4; i++)
#pragma unroll
            for (int j = 0; j < 4; j++)
                acc[i][j] = __builtin_amdgcn_mfma_f32_16x16x32_bf16(a[i], b[j], acc[i][j], 0, 0, 0);
        if (kt + 32 < DD) AWRITE(cur ^ 1);     // vmcnt-waits A loads, ds_write
        cur ^= 1;
    }

    float bias[4];
#pragma unroll
    for (int j = 0; j < 4; j++) bias[j] = bup[e * HH + n0 + wn + j * 16 + mrow];
#pragma unroll
    for (int i = 0; i < 4; i++) {
#pragma unroll
        for (int r = 0; r < 4; r++) {
            int m = m0 + wm + i * 16 + kq * 4 + r;
            if (m < cnt) {
                unsigned short* hrow = hbuf + (size_t)(off_e + m) * HH + n0 + wn + mrow;
#pragma unroll
                for (int j = 0; j < 4; j++) {
                    float v = acc[i][j][r] + bias[j];
                    v = v / (1.f + __expf(-v));   // silu
                    hrow[j * 16] = f2bf(v);
                }
            }
        }
    }
}

// ---- down GEMM: out[token] = h @ Wdown[e]^T + bdown[e], fp32 scatter-out ----
// 1-D grid of 768; XCD-region decode (see comment above).
__global__ __launch_bounds__(256) void down_gemm(const unsigned short* __restrict__ hbuf,
                                                 const unsigned short* __restrict__ Wdb,
                                                 const float* __restrict__ bdown,
                                                 const int* __restrict__ counts,
                                                 const int* __restrict__ tlist,
                                                 float* __restrict__ out) {
    // region decode: lin = g*256 + i*8 + rm ; region r = g*8 + rm (18 regions
    // of 4 slots x 8 n-blocks); member i: slot = 4r + (i&3), nb = i>>2.
    const int lin = blockIdx.x;
    const int rm = lin & 7;
    const int g  = lin >> 8;
    const int i_ = (lin >> 3) & 31;
    const int r  = g * 8 + rm;
    if (r >= (SLOTS / 4)) return;
    const int slot_id = r * 4 + (i_ & 3);
    const int nb = i_ >> 2;

    SlotDec sd = decode_slot(counts, slot_id);
    if (!sd.ok) return;
    const int e = sd.e, off_e = sd.off_e, cnt = sd.cnt, m0 = sd.m0;
    const int n0 = nb * 128;
    const int t = threadIdx.x;

    __shared__ unsigned short sA[2][128 * 32];   // 2 x 8 KB
    __shared__ unsigned short sB[2][128 * 32];   // 2 x 8 KB

    const int r0 = t >> 2;
    const int kc = (t & 3) ^ ((r0 >> 1) & 3);
    const int c1 = cnt - 1;
    int ra = m0 + r0;      if (ra > c1) ra = c1;
    int rb = m0 + 64 + r0; if (rb > c1) rb = c1;
    const unsigned short* gA0 = hbuf + (size_t)(off_e + ra) * HH + kc * 8;
    const unsigned short* gA1 = hbuf + (size_t)(off_e + rb) * HH + kc * 8;
    const unsigned short* gB0 = Wdb + ((size_t)e * DD + n0 + r0) * HH + kc * 8;
    const unsigned short* gB1 = Wdb + ((size_t)e * DD + n0 + 64 + r0) * HH + kc * 8;

    const int lane = t & 63;
    const int wm = ((t >> 6) & 1) * 64;
    const int wn = (t >> 7) * 64;
    const int mrow = lane & 15;
    const int kq = lane >> 4;
    const int slot = (kq ^ ((mrow >> 1) & 3)) * 8;

    f32x4 acc[4][4];
#pragma unroll
    for (int i = 0; i < 4; i++)
#pragma unroll
        for (int j = 0; j < 4; j++)
            acc[i][j] = (f32x4){0.f, 0.f, 0.f, 0.f};

    auto STAGE = [&](int buf, int kt) {
        gload_lds16(gA0 + kt, &sA[buf][t * 8]);
        gload_lds16(gA1 + kt, &sA[buf][(t + 256) * 8]);
        gload_lds16(gB0 + kt, &sB[buf][t * 8]);
        gload_lds16(gB1 + kt, &sB[buf][(t + 256) * 8]);
    };

    STAGE(0, 0);
    int cur = 0;
    for (int kt = 0; kt < HH; kt += 32) {
        __syncthreads();                       // drains stage(cur) + prior reads
        if (kt + 32 < HH) STAGE(cur ^ 1, kt + 32);
        short8 a[4], b[4];
#pragma unroll
        for (int i = 0; i < 4; i++) {
            a[i] = *(const short8*)(&sA[cur][(wm + i * 16 + mrow) * 32 + slot]);
            b[i] = *(const short8*)(&sB[cur][(wn + i * 16 + mrow) * 32 + slot]);
        }
#pragma unroll
        for (int i = 0; i < 4; i++)
#pragma unroll
            for (int j = 0; j < 4; j++)
                acc[i][j] = __builtin_amdgcn_mfma_f32_16x16x32_bf16(a[i], b[j], acc[i][j], 0, 0, 0);
        cur ^= 1;
    }

    const int* tl = tlist + e * NT;
    float bias[4];
#pragma unroll
    for (int j = 0; j < 4; j++) bias[j] = bdown[e * DD + n0 + wn + j * 16 + mrow];
#pragma unroll
    for (int i = 0; i < 4; i++) {
#pragma unroll
        for (int r2 = 0; r2 < 4; r2++) {
            int m = m0 + wm + i * 16 + kq * 4 + r2;
            if (m < cnt) {
                int token = tl[m];
                float* orow = out + (size_t)token * DD + n0 + wn + mrow;
#pragma unroll
                for (int j = 0; j < 4; j++)
                    orow[j * 16] = acc[i][j][r2] + bias[j];
            }
        }
    }
}

extern "C" void kernel_launch(void* const* d_in, const int* in_sizes, int n_in,
                              void* d_out, int out_size, void* d_ws, size_t ws_size,
                              hipStream_t stream) {
    const float* x     = (const float*)d_in[0];
    const float* Wr    = (const float*)d_in[1];
    const float* br    = (const float*)d_in[2];
    const float* Wup   = (const float*)d_in[3];
    const float* bup   = (const float*)d_in[4];
    const float* Wdown = (const float*)d_in[5];
    const float* bdown = (const float*)d_in[6];
    float* out = (float*)d_out;

    char* w = (char*)d_ws;
    int* counts  = (int*)w;               w += 256;
    int* tlist   = (int*)w;               w += (size_t)EE * NT * 4;
    unsigned short* hbuf = (unsigned short*)w;  w += (size_t)NT * HH * 2;
    unsigned short* Wub  = (unsigned short*)w;  w += (size_t)EE * HH * DD * 2;
    unsigned short* Wdb  = (unsigned short*)w;

    hipMemsetAsync(counts, 0, EE * sizeof(int), stream);

    // prep: 2048 router blocks + 32768 convert blocks in one launch
    prep_kernel<<<RB + (2 * (size_t)EE * HH * DD) / 2048, 256, 0, stream>>>(
        x, Wr, br, Wup, Wdown, counts, tlist, Wub, Wdb);

    dim3 gu(HH / 128, SLOTS);
    up_gemm<<<gu, 256, 0, stream>>>(x, tlist, Wub, bup, counts, hbuf);
    // down: XCD-region-mapped 1-D grid: id space 3*256 = 768 (18 regions of
    // 32 blocks + early-out holes).
    down_gemm<<<768, 256, 0, stream>>>(hbuf, Wdb, bdown, counts, tlist, out);
}